// Round 1
// baseline (3921.939 us; speedup 1.0000x reference)
//
#include <hip/hip_runtime.h>

#define NROW 32768
#define DIM  256
#define NC   8192
#define LOSS_SCALE (1.0f / 8388608.0f)

// ---------------- prep kernels ----------------

__global__ void row_norms_k(const float* __restrict__ x, float* __restrict__ norms) {
    int row  = blockIdx.x * 4 + (threadIdx.x >> 6);
    int lane = threadIdx.x & 63;
    const float4 v = ((const float4*)(x + (size_t)row * DIM))[lane];
    float s = v.x * v.x + v.y * v.y + v.z * v.z + v.w * v.w;
#pragma unroll
    for (int off = 32; off; off >>= 1) s += __shfl_down(s, off, 64);
    if (lane == 0) norms[row] = s;
}

__global__ void code_norms_k(const float* __restrict__ e, float* __restrict__ cHalf) {
    int j = blockIdx.x * 256 + threadIdx.x;
    float s = 0.f;
    for (int d = 0; d < DIM; ++d) { float v = e[(size_t)d * NC + j]; s += v * v; }
    cHalf[j] = 0.5f * s;
}

__global__ void transpose_k(const float* __restrict__ e, float* __restrict__ eT) {
    __shared__ float t[32][33];
    int jb = blockIdx.x * 32, db = blockIdx.y * 32;
#pragma unroll
    for (int i = 0; i < 4; ++i)
        t[threadIdx.y + i * 8][threadIdx.x] =
            e[(size_t)(db + threadIdx.y + i * 8) * NC + jb + threadIdx.x];
    __syncthreads();
#pragma unroll
    for (int i = 0; i < 4; ++i)
        eT[(size_t)(jb + threadIdx.y + i * 8) * DIM + db + threadIdx.x] =
            t[threadIdx.x][threadIdx.y + i * 8];
}

// ---------------- main kernel ----------------
// Tile: 64 rows x 64 codes per block, full K=256 accumulated per code-chunk.
// score s = x.e - 0.5*||e||^2 ; argmax s == argmin dist. Running argmax in regs.
// LDS: As[2][32k x 68(row-pad)] streamed, Bs[2][32k x 64j]. 1 barrier / chunk.

__global__ __launch_bounds__(256, 4) void vq_main_k(
    const float* __restrict__ x, const float* __restrict__ e,
    const float* __restrict__ eT, const float* __restrict__ norms,
    const float* __restrict__ cHalf, float* __restrict__ qout,
    float* __restrict__ iout, float* __restrict__ lout, int useT)
{
    __shared__ float  As[2][32 * 68];
    __shared__ float4 Bs[2][512];

    const int tid  = threadIdx.x;
    const int row0 = blockIdx.x * 64;
    const int ty = tid >> 4, tx = tid & 15;
    const int ar = tid >> 2, ak = (tid & 3) * 4;   // A staging: row, k-quad
    const int bk = tid >> 4, bj = tid & 15;        // B staging: k, j-quad

    float bestv[4];
    int   bestj[4];
#pragma unroll
    for (int i = 0; i < 4; ++i) { bestv[i] = -3.4e38f; bestj[i] = 0; }

    float acc[4][4];

    // prefetch chunk 0
    float4 pa0, pa1, pb0, pb1;
    {
        const float* xp = x + (size_t)(row0 + ar) * DIM + ak;
        pa0 = *(const float4*)xp;
        pa1 = *(const float4*)(xp + 16);
        const float* ep = e + (size_t)bk * NC + bj * 4;
        pb0 = *(const float4*)ep;
        pb1 = *(const float4*)(ep + 16 * NC);
    }

    int buf = 0;
    for (int c = 0; c < 1024; ++c) {        // 128 j-chunks * 8 k-chunks
        const int kc = c & 7;
        // store prefetched chunk c into As/Bs[buf]
#pragma unroll
        for (int q = 0; q < 4; ++q) As[buf][(ak + q) * 68 + ar]      = ((const float*)&pa0)[q];
#pragma unroll
        for (int q = 0; q < 4; ++q) As[buf][(16 + ak + q) * 68 + ar] = ((const float*)&pa1)[q];
        Bs[buf][bk * 16 + bj]        = pb0;
        Bs[buf][(bk + 16) * 16 + bj] = pb1;
        __syncthreads();

        // prefetch chunk c+1 (in flight during compute)
        if (c + 1 < 1024) {
            int j0n  = ((c + 1) >> 3) * 64;
            int kk0n = ((c + 1) & 7) * 32;
            const float* xp = x + (size_t)(row0 + ar) * DIM + kk0n + ak;
            pa0 = *(const float4*)xp;
            pa1 = *(const float4*)(xp + 16);
            const float* ep = e + (size_t)(kk0n + bk) * NC + j0n + bj * 4;
            pb0 = *(const float4*)ep;
            pb1 = *(const float4*)(ep + 16 * NC);
        }

        if (kc == 0) {
#pragma unroll
            for (int i = 0; i < 4; ++i)
#pragma unroll
                for (int j = 0; j < 4; ++j) acc[i][j] = 0.f;
        }

#pragma unroll
        for (int k = 0; k < 32; ++k) {
            float4 a = *(const float4*)&As[buf][k * 68 + ty * 4];
            float4 b = *(const float4*)&Bs[buf][k * 16 + tx];
            acc[0][0] += a.x * b.x; acc[0][1] += a.x * b.y; acc[0][2] += a.x * b.z; acc[0][3] += a.x * b.w;
            acc[1][0] += a.y * b.x; acc[1][1] += a.y * b.y; acc[1][2] += a.y * b.z; acc[1][3] += a.y * b.w;
            acc[2][0] += a.z * b.x; acc[2][1] += a.z * b.y; acc[2][2] += a.z * b.z; acc[2][3] += a.z * b.w;
            acc[3][0] += a.w * b.x; acc[3][1] += a.w * b.y; acc[3][2] += a.w * b.z; acc[3][3] += a.w * b.w;
        }

        if (kc == 7) {
            int j0 = (c >> 3) * 64;
            float4 ch = *(const float4*)&cHalf[j0 + tx * 4];
            int jb0 = j0 + tx * 4;
#pragma unroll
            for (int i = 0; i < 4; ++i) {
#pragma unroll
                for (int j = 0; j < 4; ++j) {
                    float s = acc[i][j] - ((const float*)&ch)[j];
                    if (s > bestv[i]) { bestv[i] = s; bestj[i] = jb0 + j; }  // strict > : earliest j wins
                }
            }
        }
        buf ^= 1;
    }

    // -------- reduce argmax across the 16 column-threads per row --------
    __syncthreads();                       // LDS free for reuse
    float* redv   = &As[0][0];             // 64 rows * 16
    int*   redj   = (int*)&As[0][1024];
    int*   idxbuf = (int*)&As[1][0];
#pragma unroll
    for (int i = 0; i < 4; ++i) {
        int r = ty * 4 + i;
        redv[r * 16 + tx] = bestv[i];
        redj[r * 16 + tx] = bestj[i];
    }
    __syncthreads();
    if (tid < 64) {
        float bv = redv[tid * 16];
        int   bj2 = redj[tid * 16];
#pragma unroll
        for (int t = 1; t < 16; ++t) {
            float v = redv[tid * 16 + t];
            int   j = redj[tid * 16 + t];
            if (v > bv || (v == bv && j < bj2)) { bv = v; bj2 = j; }
        }
        iout[row0 + tid] = (float)bj2;
        idxbuf[tid] = bj2;
        float rl = norms[row0 + tid] - 2.0f * bv;   // = ||x-e_sel||^2
#pragma unroll
        for (int off = 32; off; off >>= 1) rl += __shfl_down(rl, off, 64);
        if (tid == 0) atomicAdd(lout, rl * LOSS_SCALE);
    }
    __syncthreads();

    // -------- gather winning codes -> quantize output --------
    {
        const int rr = tid >> 6, lane = tid & 63;
        for (int r = rr; r < 64; r += 4) {
            int j = idxbuf[r];
            float4 v;
            if (useT) {
                v = *(const float4*)&eT[(size_t)j * DIM + lane * 4];
            } else {
                int d = lane * 4;
                v.x = e[(size_t)d * NC + j];
                v.y = e[(size_t)(d + 1) * NC + j];
                v.z = e[(size_t)(d + 2) * NC + j];
                v.w = e[(size_t)(d + 3) * NC + j];
            }
            *(float4*)&qout[(size_t)(row0 + r) * DIM + lane * 4] = v;
        }
    }
}

extern "C" void kernel_launch(void* const* d_in, const int* in_sizes, int n_in,
                              void* d_out, int out_size, void* d_ws, size_t ws_size,
                              hipStream_t stream) {
    const float* x = (const float*)d_in[0];   // [32768, 256] flattened input
    const float* e = (const float*)d_in[1];   // [256, 8192]

    float* qout = (float*)d_out;              // 8388608 floats
    float* iout = qout + (size_t)NROW * DIM;  // 32768 floats (indices as float)
    float* lout = iout + NROW;                // 1 float (loss)

    float* ws    = (float*)d_ws;
    float* norms = ws;                        // 32768
    float* cHalf = ws + NROW;                 // 8192
    float* eT    = ws + NROW + NC;            // 8192*256

    size_t need_base = (size_t)(NROW + NC) * sizeof(float);
    size_t need_T    = need_base + (size_t)NC * DIM * sizeof(float);
    int useT = (ws_size >= need_T) ? 1 : 0;

    hipMemsetAsync(lout, 0, sizeof(float), stream);   // loss accumulator (d_out is poisoned)
    row_norms_k<<<NROW / 4, 256, 0, stream>>>(x, norms);
    code_norms_k<<<NC / 256, 256, 0, stream>>>(e, cHalf);
    if (useT)
        transpose_k<<<dim3(NC / 32, DIM / 32), dim3(32, 8), 0, stream>>>(e, eT);
    vq_main_k<<<NROW / 64, 256, 0, stream>>>(x, e, eT, norms, cHalf, qout, iout, lout, useT);
}

// Round 3
// 666.928 us; speedup vs baseline: 5.8806x; 5.8806x over previous
//
#include <hip/hip_runtime.h>
#include <hip/hip_fp16.h>

#define NROW 32768
#define DIM  256
#define NC   8192
#define LOSS_SCALE (1.0f / 8388608.0f)

typedef __attribute__((ext_vector_type(8))) _Float16 half8;
typedef __attribute__((ext_vector_type(4))) float   floatx4;
typedef const __attribute__((address_space(1))) void* gas_p;
typedef __attribute__((address_space(3))) void*       las_p;

// ======================= prep kernels (fast path) =======================

// rows -> norms + A' = [xhi | xlo] as f16, row stride 512
__global__ void prep_a_k(const float* __restrict__ x, unsigned short* __restrict__ Ah,
                         float* __restrict__ norms) {
    int row  = blockIdx.x * 4 + (threadIdx.x >> 6);
    int lane = threadIdx.x & 63;
    const float4 v = ((const float4*)(x + (size_t)row * DIM))[lane];
    float s = v.x * v.x + v.y * v.y + v.z * v.z + v.w * v.w;
#pragma unroll
    for (int off = 32; off; off >>= 1) s += __shfl_down(s, off, 64);
    if (lane == 0) norms[row] = s;
    __half h0 = __float2half(v.x), h1 = __float2half(v.y),
           h2 = __float2half(v.z), h3 = __float2half(v.w);
    __half l0 = __float2half(v.x - __half2float(h0));
    __half l1 = __float2half(v.y - __half2float(h1));
    __half l2 = __float2half(v.z - __half2float(h2));
    __half l3 = __float2half(v.w - __half2float(h3));
    ushort4 hi4 = make_ushort4(__half_as_ushort(h0), __half_as_ushort(h1),
                               __half_as_ushort(h2), __half_as_ushort(h3));
    ushort4 lo4 = make_ushort4(__half_as_ushort(l0), __half_as_ushort(l1),
                               __half_as_ushort(l2), __half_as_ushort(l3));
    *(ushort4*)(Ah + (size_t)row * 512 + lane * 4)       = hi4;
    *(ushort4*)(Ah + (size_t)row * 512 + 256 + lane * 4) = lo4;
}

__global__ void code_norms_k(const float* __restrict__ e, float* __restrict__ cHalf) {
    int j = blockIdx.x * 256 + threadIdx.x;
    float s = 0.f;
    for (int d = 0; d < DIM; ++d) { float v = e[(size_t)d * NC + j]; s += v * v; }
    cHalf[j] = 0.5f * s;
}

// e [dim][code] -> eT fp32 [code][dim]  and  B' = [ehi | elo | ehi] f16, row stride 768
__global__ void prep_b_k(const float* __restrict__ e, float* __restrict__ eT,
                         unsigned short* __restrict__ Bh) {
    __shared__ float t[32][33];
    int jb = blockIdx.x * 32, db = blockIdx.y * 32;
#pragma unroll
    for (int i = 0; i < 4; ++i)
        t[threadIdx.y + i * 8][threadIdx.x] =
            e[(size_t)(db + threadIdx.y + i * 8) * NC + jb + threadIdx.x];
    __syncthreads();
#pragma unroll
    for (int i = 0; i < 4; ++i) {
        int j = jb + threadIdx.y + i * 8;
        int d = db + threadIdx.x;
        float val = t[threadIdx.x][threadIdx.y + i * 8];
        eT[(size_t)j * DIM + d] = val;
        __half h = __float2half(val);
        __half l = __float2half(val - __half2float(h));
        unsigned short hu = __half_as_ushort(h), lu = __half_as_ushort(l);
        Bh[(size_t)j * 768 + d]       = hu;
        Bh[(size_t)j * 768 + 256 + d] = lu;
        Bh[(size_t)j * 768 + 512 + d] = hu;
    }
}

// ======================= main MFMA kernel =======================
// grid 1024: blockIdx = rb*4 + js. Block tile 128 rows x 128 cols, scanning
// 2048 cols (j-split 4). K' = 768 in 24 chunks of 32: c 0-7 xhi.ehi,
// 8-15 xhi.elo, 16-23 xlo.ehi (A offset (c<8?c:c-8)*32 covers hi,hi,lo).
// LDS: As/Bs [2][128 rows x 32 k] f16, staged via global_load_lds width 16.
// Wave tile 64x64 = 4x4 frags of 16x16x32 f16 MFMA. Running argmax in regs.
// RACE FIX (round 3): waves sharing rows (col-half pairs) must MERGE their
// per-half argmax through LDS before writing pv/pj — round 2 had both
// col-half waves racing on the same pv[row] slot (last-writer-wins dropped
// half the column space for every row).

__global__ __launch_bounds__(256, 2) void vq_mfma_k(
    const unsigned short* __restrict__ Ah, const unsigned short* __restrict__ Bh,
    const float* __restrict__ cHalf, float* __restrict__ pv, int* __restrict__ pj)
{
    __shared__ __align__(16) _Float16 As[2][4096];
    __shared__ __align__(16) _Float16 Bs[2][4096];

    const int tid  = threadIdx.x;
    const int js   = blockIdx.x & 3;
    const int rb   = blockIdx.x >> 2;
    const int row0 = rb * 128, col0 = js * 2048;
    const int lane = tid & 63, l15 = lane & 15, lq = lane >> 4;
    const int wave = tid >> 6;
    const int wrow = (wave >> 1) * 64, wcol = (wave & 1) * 64;
    const int sr = tid >> 2, sp = (tid & 3) * 8;   // staging: row, k-part(8 halves)

    float bv[16];
    int   bj[16];
#pragma unroll
    for (int s = 0; s < 16; ++s) { bv[s] = -3.4e38f; bj[s] = 0; }

    const floatx4 fzero = {0.0f, 0.0f, 0.0f, 0.0f};
    const unsigned short* Abase = Ah + (size_t)(row0 + sr) * 512 + sp;

    for (int jt = 0; jt < 16; ++jt) {
        floatx4 acc[4][4];
#pragma unroll
        for (int rf = 0; rf < 4; ++rf)
#pragma unroll
            for (int cf = 0; cf < 4; ++cf) acc[rf][cf] = fzero;

        const unsigned short* Bbase = Bh + (size_t)(col0 + jt * 128 + sr) * 768 + sp;

        for (int c = 0; c < 24; ++c) {
            const int buf = c & 1;
            const int ac = (c < 8 ? c : c - 8) * 32;
            const int bc = c * 32;
            _Float16* la = &As[buf][tid * 8];
            _Float16* lb = &Bs[buf][tid * 8];
            __builtin_amdgcn_global_load_lds((gas_p)(Abase + ac),            (las_p)la,          16, 0, 0);
            __builtin_amdgcn_global_load_lds((gas_p)(Abase + 64 * 512 + ac), (las_p)(la + 2048), 16, 0, 0);
            __builtin_amdgcn_global_load_lds((gas_p)(Bbase + bc),            (las_p)lb,          16, 0, 0);
            __builtin_amdgcn_global_load_lds((gas_p)(Bbase + 64 * 768 + bc), (las_p)(lb + 2048), 16, 0, 0);
            __syncthreads();

            half8 af[4], bf[4];
#pragma unroll
            for (int rf = 0; rf < 4; ++rf)
                af[rf] = *(const half8*)&As[buf][(wrow + rf * 16 + l15) * 32 + lq * 8];
#pragma unroll
            for (int cf = 0; cf < 4; ++cf)
                bf[cf] = *(const half8*)&Bs[buf][(wcol + cf * 16 + l15) * 32 + lq * 8];
#pragma unroll
            for (int rf = 0; rf < 4; ++rf)
#pragma unroll
                for (int cf = 0; cf < 4; ++cf)
                    acc[rf][cf] = __builtin_amdgcn_mfma_f32_16x16x32_f16(
                        af[rf], bf[cf], acc[rf][cf], 0, 0, 0);
            // dbuf: next iteration writes the other buffer; barrier c+1's
            // lgkmcnt(0) drain protects buffer reuse two iterations out.
        }

        // epilogue: score = acc - cHalf[col]; running argmax (ascending j, strict >)
        const int colbase = col0 + jt * 128 + wcol;
#pragma unroll
        for (int cf = 0; cf < 4; ++cf) {
            const int col = colbase + cf * 16 + l15;
            const float ch = cHalf[col];
#pragma unroll
            for (int rf = 0; rf < 4; ++rf)
#pragma unroll
                for (int r = 0; r < 4; ++r) {
                    float s = acc[rf][cf][r] - ch;
                    int slot = rf * 4 + r;
                    if (s > bv[slot]) { bv[slot] = s; bj[slot] = col; }
                }
        }
    }

    // cross-lane argmax over the 16 lanes of each row-group (same lq)
#pragma unroll
    for (int st = 1; st < 16; st <<= 1) {
#pragma unroll
        for (int s = 0; s < 16; ++s) {
            float v2 = __shfl_xor(bv[s], st, 64);
            int   j2 = __shfl_xor(bj[s], st, 64);
            if (v2 > bv[s] || (v2 == bv[s] && j2 < bj[s])) { bv[s] = v2; bj[s] = j2; }
        }
    }

    // -------- merge the two column-half waves per row through LDS --------
    __syncthreads();                         // all LDS reads of last chunk done
    float* mv = (float*)&As[0][0];           // [128 rows][2 col-halves]
    int*   mj = (int*)&Bs[0][0];
    if (l15 == 0) {
#pragma unroll
        for (int rf = 0; rf < 4; ++rf)
#pragma unroll
            for (int r = 0; r < 4; ++r) {
                int rloc = wrow + rf * 16 + lq * 4 + r;
                int slot = rf * 4 + r;
                mv[rloc * 2 + (wave & 1)] = bv[slot];
                mj[rloc * 2 + (wave & 1)] = bj[slot];
            }
    }
    __syncthreads();
    if (tid < 128) {
        float v0 = mv[tid * 2],     v1 = mv[tid * 2 + 1];
        int   j0 = mj[tid * 2],     j1 = mj[tid * 2 + 1];
        bool take1 = (v1 > v0) || (v1 == v0 && j1 < j0);   // smaller index on tie
        pv[(size_t)js * NROW + row0 + tid] = take1 ? v1 : v0;
        pj[(size_t)js * NROW + row0 + tid] = take1 ? j1 : j0;
    }
}

// ======================= reduce + gather + loss =======================

__global__ void vq_reduce_k(const float* __restrict__ pv, const int* __restrict__ pj,
                            const float* __restrict__ norms, const float* __restrict__ eT,
                            float* __restrict__ qout, float* __restrict__ iout,
                            float* __restrict__ lout)
{
    __shared__ int jbuf[64];
    const int row0 = blockIdx.x * 64;
    const int tid = threadIdx.x;
    if (tid < 64) {
        int row = row0 + tid;
        float bvv = pv[row]; int bjj = pj[row];
#pragma unroll
        for (int s = 1; s < 4; ++s) {
            float v = pv[(size_t)s * NROW + row];
            int   j = pj[(size_t)s * NROW + row];
            if (v > bvv || (v == bvv && j < bjj)) { bvv = v; bjj = j; }
        }
        iout[row] = (float)bjj;
        jbuf[tid] = bjj;
        float rl = norms[row] - 2.0f * bvv;   // ||x - e_sel||^2
#pragma unroll
        for (int off = 32; off; off >>= 1) rl += __shfl_down(rl, off, 64);
        if (tid == 0) atomicAdd(lout, rl * LOSS_SCALE);
    }
    __syncthreads();
    const int lane = tid & 63;
    for (int r = tid >> 6; r < 64; r += 4) {
        int j = jbuf[r];
        float4 v = *(const float4*)&eT[(size_t)j * DIM + lane * 4];
        *(float4*)&qout[(size_t)(row0 + r) * DIM + lane * 4] = v;
    }
}

// ======================= fallback fp32 path (round-1, known-good) =======================

__global__ void transpose_k(const float* __restrict__ e, float* __restrict__ eT) {
    __shared__ float t[32][33];
    int jb = blockIdx.x * 32, db = blockIdx.y * 32;
#pragma unroll
    for (int i = 0; i < 4; ++i)
        t[threadIdx.y + i * 8][threadIdx.x] =
            e[(size_t)(db + threadIdx.y + i * 8) * NC + jb + threadIdx.x];
    __syncthreads();
#pragma unroll
    for (int i = 0; i < 4; ++i)
        eT[(size_t)(jb + threadIdx.y + i * 8) * DIM + db + threadIdx.x] =
            t[threadIdx.x][threadIdx.y + i * 8];
}

__global__ void row_norms_k(const float* __restrict__ x, float* __restrict__ norms) {
    int row  = blockIdx.x * 4 + (threadIdx.x >> 6);
    int lane = threadIdx.x & 63;
    const float4 v = ((const float4*)(x + (size_t)row * DIM))[lane];
    float s = v.x * v.x + v.y * v.y + v.z * v.z + v.w * v.w;
#pragma unroll
    for (int off = 32; off; off >>= 1) s += __shfl_down(s, off, 64);
    if (lane == 0) norms[row] = s;
}

__global__ __launch_bounds__(256, 4) void vq_main_k(
    const float* __restrict__ x, const float* __restrict__ e,
    const float* __restrict__ eT, const float* __restrict__ norms,
    const float* __restrict__ cHalf, float* __restrict__ qout,
    float* __restrict__ iout, float* __restrict__ lout, int useT)
{
    __shared__ float  As[2][32 * 68];
    __shared__ float4 Bs[2][512];
    const int tid  = threadIdx.x;
    const int row0 = blockIdx.x * 64;
    const int ty = tid >> 4, tx = tid & 15;
    const int ar = tid >> 2, ak = (tid & 3) * 4;
    const int bk = tid >> 4, bj = tid & 15;
    float bestv[4]; int bestj[4];
#pragma unroll
    for (int i = 0; i < 4; ++i) { bestv[i] = -3.4e38f; bestj[i] = 0; }
    float acc[4][4];
    float4 pa0, pa1, pb0, pb1;
    {
        const float* xp = x + (size_t)(row0 + ar) * DIM + ak;
        pa0 = *(const float4*)xp;
        pa1 = *(const float4*)(xp + 16);
        const float* ep = e + (size_t)bk * NC + bj * 4;
        pb0 = *(const float4*)ep;
        pb1 = *(const float4*)(ep + 16 * NC);
    }
    int buf = 0;
    for (int c = 0; c < 1024; ++c) {
        const int kc = c & 7;
#pragma unroll
        for (int q = 0; q < 4; ++q) As[buf][(ak + q) * 68 + ar]      = ((const float*)&pa0)[q];
#pragma unroll
        for (int q = 0; q < 4; ++q) As[buf][(16 + ak + q) * 68 + ar] = ((const float*)&pa1)[q];
        Bs[buf][bk * 16 + bj]        = pb0;
        Bs[buf][(bk + 16) * 16 + bj] = pb1;
        __syncthreads();
        if (c + 1 < 1024) {
            int j0n  = ((c + 1) >> 3) * 64;
            int kk0n = ((c + 1) & 7) * 32;
            const float* xp = x + (size_t)(row0 + ar) * DIM + kk0n + ak;
            pa0 = *(const float4*)xp;
            pa1 = *(const float4*)(xp + 16);
            const float* ep = e + (size_t)(kk0n + bk) * NC + j0n + bj * 4;
            pb0 = *(const float4*)ep;
            pb1 = *(const float4*)(ep + 16 * NC);
        }
        if (kc == 0) {
#pragma unroll
            for (int i = 0; i < 4; ++i)
#pragma unroll
                for (int j = 0; j < 4; ++j) acc[i][j] = 0.f;
        }
#pragma unroll
        for (int k = 0; k < 32; ++k) {
            float4 a = *(const float4*)&As[buf][k * 68 + ty * 4];
            float4 b = *(const float4*)&Bs[buf][k * 16 + tx];
            acc[0][0] += a.x * b.x; acc[0][1] += a.x * b.y; acc[0][2] += a.x * b.z; acc[0][3] += a.x * b.w;
            acc[1][0] += a.y * b.x; acc[1][1] += a.y * b.y; acc[1][2] += a.y * b.z; acc[1][3] += a.y * b.w;
            acc[2][0] += a.z * b.x; acc[2][1] += a.z * b.y; acc[2][2] += a.z * b.z; acc[2][3] += a.z * b.w;
            acc[3][0] += a.w * b.x; acc[3][1] += a.w * b.y; acc[3][2] += a.w * b.z; acc[3][3] += a.w * b.w;
        }
        if (kc == 7) {
            int j0 = (c >> 3) * 64;
            float4 ch = *(const float4*)&cHalf[j0 + tx * 4];
            int jb0 = j0 + tx * 4;
#pragma unroll
            for (int i = 0; i < 4; ++i)
#pragma unroll
                for (int j = 0; j < 4; ++j) {
                    float s = acc[i][j] - ((const float*)&ch)[j];
                    if (s > bestv[i]) { bestv[i] = s; bestj[i] = jb0 + j; }
                }
        }
        buf ^= 1;
    }
    __syncthreads();
    float* redv   = &As[0][0];
    int*   redj   = (int*)&As[0][1024];
    int*   idxbuf = (int*)&As[1][0];
#pragma unroll
    for (int i = 0; i < 4; ++i) {
        int r = ty * 4 + i;
        redv[r * 16 + tx] = bestv[i];
        redj[r * 16 + tx] = bestj[i];
    }
    __syncthreads();
    if (tid < 64) {
        float bvv = redv[tid * 16];
        int   bj2 = redj[tid * 16];
#pragma unroll
        for (int t = 1; t < 16; ++t) {
            float v = redv[tid * 16 + t];
            int   j = redj[tid * 16 + t];
            if (v > bvv || (v == bvv && j < bj2)) { bvv = v; bj2 = j; }
        }
        iout[row0 + tid] = (float)bj2;
        idxbuf[tid] = bj2;
        float rl = norms[row0 + tid] - 2.0f * bvv;
#pragma unroll
        for (int off = 32; off; off >>= 1) rl += __shfl_down(rl, off, 64);
        if (tid == 0) atomicAdd(lout, rl * LOSS_SCALE);
    }
    __syncthreads();
    {
        const int rr = tid >> 6, lane = tid & 63;
        for (int r = rr; r < 64; r += 4) {
            int j = idxbuf[r];
            float4 v;
            if (useT) {
                v = *(const float4*)&eT[(size_t)j * DIM + lane * 4];
            } else {
                int d = lane * 4;
                v.x = e[(size_t)d * NC + j];
                v.y = e[(size_t)(d + 1) * NC + j];
                v.z = e[(size_t)(d + 2) * NC + j];
                v.w = e[(size_t)(d + 3) * NC + j];
            }
            *(float4*)&qout[(size_t)(row0 + r) * DIM + lane * 4] = v;
        }
    }
}

// ======================= launch =======================

extern "C" void kernel_launch(void* const* d_in, const int* in_sizes, int n_in,
                              void* d_out, int out_size, void* d_ws, size_t ws_size,
                              hipStream_t stream) {
    const float* x = (const float*)d_in[0];   // [32768, 256]
    const float* e = (const float*)d_in[1];   // [256, 8192]

    float* qout = (float*)d_out;
    float* iout = qout + (size_t)NROW * DIM;
    float* lout = iout + NROW;

    char* ws = (char*)d_ws;
    // fast-path layout
    const size_t offAh    = 0;                       // 33,554,432
    const size_t offBh    = offAh + 33554432;        // 12,582,912
    const size_t offET    = offBh + 12582912;        //  8,388,608
    const size_t offNorms = offET + 8388608;         //    131,072
    const size_t offCH    = offNorms + 131072;       //     32,768
    const size_t offPV    = offCH + 32768;           //    524,288
    const size_t offPJ    = offPV + 524288;          //    524,288
    const size_t needFast = offPJ + 524288;          // 55,738,368

    hipMemsetAsync(lout, 0, sizeof(float), stream);

    if (ws_size >= needFast) {
        unsigned short* Ah = (unsigned short*)(ws + offAh);
        unsigned short* Bh = (unsigned short*)(ws + offBh);
        float* eT    = (float*)(ws + offET);
        float* norms = (float*)(ws + offNorms);
        float* cHalf = (float*)(ws + offCH);
        float* pv    = (float*)(ws + offPV);
        int*   pj    = (int*)(ws + offPJ);

        prep_a_k<<<NROW / 4, 256, 0, stream>>>(x, Ah, norms);
        code_norms_k<<<NC / 256, 256, 0, stream>>>(e, cHalf);
        prep_b_k<<<dim3(NC / 32, DIM / 32), dim3(32, 8), 0, stream>>>(e, eT, Bh);
        vq_mfma_k<<<1024, 256, 0, stream>>>(Ah, Bh, cHalf, pv, pj);
        vq_reduce_k<<<NROW / 64, 256, 0, stream>>>(pv, pj, norms, eT, qout, iout, lout);
    } else {
        // round-1 fp32 fallback
        float* fws   = (float*)d_ws;
        float* norms = fws;
        float* cHalf = fws + NROW;
        float* eT    = fws + NROW + NC;
        size_t need_T = (size_t)(NROW + NC) * sizeof(float) + (size_t)NC * DIM * sizeof(float);
        int useT = (ws_size >= need_T) ? 1 : 0;
        row_norms_k<<<NROW / 4, 256, 0, stream>>>(x, norms);
        code_norms_k<<<NC / 256, 256, 0, stream>>>(e, cHalf);
        if (useT)
            transpose_k<<<dim3(NC / 32, DIM / 32), dim3(32, 8), 0, stream>>>(e, eT);
        vq_main_k<<<NROW / 64, 256, 0, stream>>>(x, e, eT, norms, cHalf, qout, iout, lout, useT);
    }
}

// Round 4
// 625.129 us; speedup vs baseline: 6.2738x; 1.0669x over previous
//
#include <hip/hip_runtime.h>
#include <hip/hip_fp16.h>

#define NROW 32768
#define DIM  256
#define NC   8192
#define CAP  8192                      // max rescued rows (expect ~2500)
#define MARGIN 0.35f                   // cheap-score gap below which we rescue
#define LOSS_SCALE (1.0f / 8388608.0f)

typedef __attribute__((ext_vector_type(8))) _Float16 half8;
typedef __attribute__((ext_vector_type(4))) float   floatx4;
typedef const __attribute__((address_space(1))) void* gas_p;
typedef __attribute__((address_space(3))) void*       las_p;

// ======================= prep kernels =======================

// rows -> norms + A' = [xhi | xlo] f16, row stride 512
__global__ void prep_a_k(const float* __restrict__ x, unsigned short* __restrict__ Ah,
                         float* __restrict__ norms) {
    int row  = blockIdx.x * 4 + (threadIdx.x >> 6);
    int lane = threadIdx.x & 63;
    const float4 v = ((const float4*)(x + (size_t)row * DIM))[lane];
    float s = v.x * v.x + v.y * v.y + v.z * v.z + v.w * v.w;
#pragma unroll
    for (int off = 32; off; off >>= 1) s += __shfl_down(s, off, 64);
    if (lane == 0) norms[row] = s;
    __half h0 = __float2half(v.x), h1 = __float2half(v.y),
           h2 = __float2half(v.z), h3 = __float2half(v.w);
    __half l0 = __float2half(v.x - __half2float(h0));
    __half l1 = __float2half(v.y - __half2float(h1));
    __half l2 = __float2half(v.z - __half2float(h2));
    __half l3 = __float2half(v.w - __half2float(h3));
    ushort4 hi4 = make_ushort4(__half_as_ushort(h0), __half_as_ushort(h1),
                               __half_as_ushort(h2), __half_as_ushort(h3));
    ushort4 lo4 = make_ushort4(__half_as_ushort(l0), __half_as_ushort(l1),
                               __half_as_ushort(l2), __half_as_ushort(l3));
    *(ushort4*)(Ah + (size_t)row * 512 + lane * 4)       = hi4;
    *(ushort4*)(Ah + (size_t)row * 512 + 256 + lane * 4) = lo4;
}

__global__ void code_norms_k(const float* __restrict__ e, float* __restrict__ cHalf) {
    int j = blockIdx.x * 256 + threadIdx.x;
    float s = 0.f;
    for (int d = 0; d < DIM; ++d) { float v = e[(size_t)d * NC + j]; s += v * v; }
    cHalf[j] = 0.5f * s;
}

// e [dim][code] -> eT fp32 [code][dim]  and  B' = [ehi | elo] f16, row stride 512
__global__ void prep_b_k(const float* __restrict__ e, float* __restrict__ eT,
                         unsigned short* __restrict__ Bh) {
    __shared__ float t[32][33];
    int jb = blockIdx.x * 32, db = blockIdx.y * 32;
#pragma unroll
    for (int i = 0; i < 4; ++i)
        t[threadIdx.y + i * 8][threadIdx.x] =
            e[(size_t)(db + threadIdx.y + i * 8) * NC + jb + threadIdx.x];
    __syncthreads();
#pragma unroll
    for (int i = 0; i < 4; ++i) {
        int j = jb + threadIdx.y + i * 8;
        int d = db + threadIdx.x;
        float val = t[threadIdx.x][threadIdx.y + i * 8];
        eT[(size_t)j * DIM + d] = val;
        __half h = __float2half(val);
        __half l = __float2half(val - __half2float(h));
        Bh[(size_t)j * 512 + d]       = __half_as_ushort(h);
        Bh[(size_t)j * 512 + 256 + d] = __half_as_ushort(l);
    }
}

// ======================= templated GEMM+argmax kernel =======================
// Verified round-3 body. Block tile 128x128, wave tile 64x64 (4x4 frags of
// 16x16x32 f16 MFMA), LDS dbuf, global_load_lds width 16, 1 barrier/chunk.
// Chunk c: A off (c<8?c:c-8)*32 [hi,hi,lo], B off (c<16?c:c-16)*32 [hi,lo,hi]
//   -> c 0-7: xhi.ehi; 8-15: xhi.elo; 16-23: xlo.ehi.
// CHEAP (CHUNKS=8): hi.hi only, tracks top-1 (value+index) AND top-2 value.
// RESCUE: indirect rows via list[], early-exit past *cnt, tracks top-1.

template<int CHUNKS, int JT, int JSB, bool RESCUE>
__global__ __launch_bounds__(256, 2) void vq_gemm_k(
    const unsigned short* __restrict__ Ah, const unsigned short* __restrict__ Bh,
    const float* __restrict__ cHalf,
    float* __restrict__ pv, int* __restrict__ pj, float* __restrict__ psv,
    const int* __restrict__ list, const int* __restrict__ cnt)
{
    __shared__ __align__(16) _Float16 As[2][4096];
    __shared__ __align__(16) _Float16 Bs[2][4096];

    const int tid  = threadIdx.x;
    const int js   = blockIdx.x & ((1 << JSB) - 1);
    const int rb   = blockIdx.x >> JSB;
    const int row0 = rb * 128, col0 = js * (JT * 128);
    const int lane = tid & 63, l15 = lane & 15, lq = lane >> 4;
    const int wave = tid >> 6;
    const int wrow = (wave >> 1) * 64, wcol = (wave & 1) * 64;
    const int sr = tid >> 2, sp = (tid & 3) * 8;   // staging: row, k-part

    int nact = 0;
    if constexpr (RESCUE) {
        nact = *cnt;
        if (row0 >= nact) return;
    }

    const unsigned short *Abase0, *Abase1;
    if constexpr (RESCUE) {
        int i0 = row0 + sr, i1 = i0 + 64;
        int r0 = (i0 < nact) ? list[i0] : 0;
        int r1 = (i1 < nact) ? list[i1] : 0;
        Abase0 = Ah + (size_t)r0 * 512 + sp;
        Abase1 = Ah + (size_t)r1 * 512 + sp;
    } else {
        Abase0 = Ah + (size_t)(row0 + sr) * 512 + sp;
        Abase1 = Abase0 + 64 * 512;
    }

    float bv[16]; int bj[16]; float sv[16];
#pragma unroll
    for (int s = 0; s < 16; ++s) { bv[s] = -3.4e38f; bj[s] = 0; sv[s] = -3.4e38f; }

    const floatx4 fzero = {0.0f, 0.0f, 0.0f, 0.0f};

    for (int jt = 0; jt < JT; ++jt) {
        floatx4 acc[4][4];
#pragma unroll
        for (int rf = 0; rf < 4; ++rf)
#pragma unroll
            for (int cf = 0; cf < 4; ++cf) acc[rf][cf] = fzero;

        const unsigned short* Bbase = Bh + (size_t)(col0 + jt * 128 + sr) * 512 + sp;

        for (int c = 0; c < CHUNKS; ++c) {
            const int buf = c & 1;
            const int ac = (c < 8 ? c : c - 8) * 32;
            const int bc = (c < 16 ? c : c - 16) * 32;
            _Float16* la = &As[buf][tid * 8];
            _Float16* lb = &Bs[buf][tid * 8];
            __builtin_amdgcn_global_load_lds((gas_p)(Abase0 + ac),           (las_p)la,          16, 0, 0);
            __builtin_amdgcn_global_load_lds((gas_p)(Abase1 + ac),           (las_p)(la + 2048), 16, 0, 0);
            __builtin_amdgcn_global_load_lds((gas_p)(Bbase + bc),            (las_p)lb,          16, 0, 0);
            __builtin_amdgcn_global_load_lds((gas_p)(Bbase + 64 * 512 + bc), (las_p)(lb + 2048), 16, 0, 0);
            __syncthreads();

            half8 af[4], bf[4];
#pragma unroll
            for (int rf = 0; rf < 4; ++rf)
                af[rf] = *(const half8*)&As[buf][(wrow + rf * 16 + l15) * 32 + lq * 8];
#pragma unroll
            for (int cf = 0; cf < 4; ++cf)
                bf[cf] = *(const half8*)&Bs[buf][(wcol + cf * 16 + l15) * 32 + lq * 8];
#pragma unroll
            for (int rf = 0; rf < 4; ++rf)
#pragma unroll
                for (int cf = 0; cf < 4; ++cf)
                    acc[rf][cf] = __builtin_amdgcn_mfma_f32_16x16x32_f16(
                        af[rf], bf[cf], acc[rf][cf], 0, 0, 0);
        }

        // epilogue: score = acc - cHalf[col]; ascending-col scan, strict >
        const int colbase = col0 + jt * 128 + wcol;
#pragma unroll
        for (int cf = 0; cf < 4; ++cf) {
            const int col = colbase + cf * 16 + l15;
            const float ch = cHalf[col];
#pragma unroll
            for (int rf = 0; rf < 4; ++rf)
#pragma unroll
                for (int r = 0; r < 4; ++r) {
                    float s = acc[rf][cf][r] - ch;
                    int slot = rf * 4 + r;
                    if constexpr (RESCUE) {
                        if (s > bv[slot]) { bv[slot] = s; bj[slot] = col; }
                    } else {
                        if (s > bv[slot])      { sv[slot] = bv[slot]; bv[slot] = s; bj[slot] = col; }
                        else if (s > sv[slot]) { sv[slot] = s; }
                    }
                }
        }
    }

    // cross-lane merge over the 16 lanes of each row-group (disjoint col sets)
#pragma unroll
    for (int st = 1; st < 16; st <<= 1) {
#pragma unroll
        for (int s = 0; s < 16; ++s) {
            float v2 = __shfl_xor(bv[s], st, 64);
            int   j2 = __shfl_xor(bj[s], st, 64);
            bool better = (v2 > bv[s]) || (v2 == bv[s] && j2 < bj[s]);
            if constexpr (!RESCUE) {
                float s2 = __shfl_xor(sv[s], st, 64);
                float loseBest = better ? bv[s] : v2;
                sv[s] = fmaxf(fmaxf(sv[s], s2), loseBest);
            }
            if (better) { bv[s] = v2; bj[s] = j2; }
        }
    }

    // merge the two column-half waves per row through LDS
    __syncthreads();
    float* mv  = (float*)&As[0][0];          // [128][2]
    float* msv = mv + 256;                   // [128][2]
    int*   mj  = (int*)&Bs[0][0];            // [128][2]
    if (l15 == 0) {
#pragma unroll
        for (int rf = 0; rf < 4; ++rf)
#pragma unroll
            for (int r = 0; r < 4; ++r) {
                int rloc = wrow + rf * 16 + lq * 4 + r;
                int slot = rf * 4 + r;
                mv[rloc * 2 + (wave & 1)] = bv[slot];
                mj[rloc * 2 + (wave & 1)] = bj[slot];
                if constexpr (!RESCUE) msv[rloc * 2 + (wave & 1)] = sv[slot];
            }
    }
    __syncthreads();
    if (tid < 128) {
        float v0 = mv[tid * 2], v1 = mv[tid * 2 + 1];
        int   j0 = mj[tid * 2], j1 = mj[tid * 2 + 1];
        bool take1 = (v1 > v0) || (v1 == v0 && j1 < j0);
        float bb = take1 ? v1 : v0;
        int   jj = take1 ? j1 : j0;
        size_t outRows = RESCUE ? (size_t)CAP : (size_t)NROW;
        pv[(size_t)js * outRows + row0 + tid] = bb;
        pj[(size_t)js * outRows + row0 + tid] = jj;
        if constexpr (!RESCUE) {
            float lose = take1 ? v0 : v1;
            float ss = fmaxf(fmaxf(msv[tid * 2], msv[tid * 2 + 1]), lose);
            psv[(size_t)js * outRows + row0 + tid] = ss;
        }
    }
}

// ======================= cheap reduce: merge splits, flag, gather =======================

__global__ void vq_reduce_k(const float* __restrict__ pv, const int* __restrict__ pj,
                            const float* __restrict__ psv,
                            const float* __restrict__ norms, const float* __restrict__ eT,
                            float* __restrict__ qout, float* __restrict__ iout,
                            float* __restrict__ lout, int* __restrict__ list,
                            int* __restrict__ cnt)
{
    __shared__ int jbuf[64];
    const int row0 = blockIdx.x * 64;
    const int tid = threadIdx.x;
    if (tid < 64) {
        int row = row0 + tid;
        float bv = pv[row]; int bj = pj[row]; float sv = psv[row];
#pragma unroll
        for (int s = 1; s < 4; ++s) {
            float v = pv[(size_t)s * NROW + row];
            int   j = pj[(size_t)s * NROW + row];
            float s2 = psv[(size_t)s * NROW + row];
            bool better = (v > bv) || (v == bv && j < bj);
            float loseBest = better ? bv : v;
            sv = fmaxf(fmaxf(sv, s2), loseBest);
            if (better) { bv = v; bj = j; }
        }
        bool flagged = (bv - sv) < MARGIN;
        if (flagged) {
            int idx = atomicAdd(cnt, 1);
            if (idx < CAP) {
                list[idx] = row;
                jbuf[tid] = -1;            // rescue pass will write this row
            } else {
                flagged = false;           // overflow fallback: accept cheap result
            }
        }
        float rl = 0.f;
        if (!flagged) {
            iout[row] = (float)bj;
            jbuf[tid] = bj;
            rl = norms[row] - 2.0f * bv;   // ||x - e_sel||^2 (cheap score; bias ~1e-7 on loss)
        }
#pragma unroll
        for (int off = 32; off; off >>= 1) rl += __shfl_down(rl, off, 64);
        if (tid == 0) atomicAdd(lout, rl * LOSS_SCALE);
    }
    __syncthreads();
    const int lane = tid & 63;
    for (int r = tid >> 6; r < 64; r += 4) {
        int j = jbuf[r];
        if (j >= 0) {
            float4 v = *(const float4*)&eT[(size_t)j * DIM + lane * 4];
            *(float4*)&qout[(size_t)(row0 + r) * DIM + lane * 4] = v;
        }
    }
}

// ======================= rescue reduce: merge 32 splits, finalize flagged rows =======================

__global__ void vq_reduce2_k(const float* __restrict__ pv2, const int* __restrict__ pj2,
                             const int* __restrict__ list, const int* __restrict__ cnt,
                             const float* __restrict__ norms, const float* __restrict__ eT,
                             float* __restrict__ qout, float* __restrict__ iout,
                             float* __restrict__ lout)
{
    __shared__ int rbuf[64], jb2[64];
    const int n = *cnt < CAP ? *cnt : CAP;
    const int i0 = blockIdx.x * 64;
    if (i0 >= n) return;
    const int tid = threadIdx.x;
    if (tid < 64) {
        int i = i0 + tid;
        float rl = 0.f;
        if (i < n) {
            float bv = pv2[i]; int bj = pj2[i];
#pragma unroll 4
            for (int s = 1; s < 32; ++s) {
                float v = pv2[(size_t)s * CAP + i];
                int   j = pj2[(size_t)s * CAP + i];
                if (v > bv || (v == bv && j < bj)) { bv = v; bj = j; }
            }
            int row = list[i];
            iout[row] = (float)bj;
            rbuf[tid] = row;
            jb2[tid]  = bj;
            rl = norms[row] - 2.0f * bv;   // precise score
        } else {
            rbuf[tid] = -1;
        }
#pragma unroll
        for (int off = 32; off; off >>= 1) rl += __shfl_down(rl, off, 64);
        if (tid == 0) atomicAdd(lout, rl * LOSS_SCALE);
    }
    __syncthreads();
    const int lane = tid & 63;
    for (int r = tid >> 6; r < 64; r += 4) {
        int row = rbuf[r];
        if (row >= 0) {
            float4 v = *(const float4*)&eT[(size_t)jb2[r] * DIM + lane * 4];
            *(float4*)&qout[(size_t)row * DIM + lane * 4] = v;
        }
    }
}

// ======================= fallback fp32 path (round-1, known-good) =======================

__global__ void transpose_k(const float* __restrict__ e, float* __restrict__ eT) {
    __shared__ float t[32][33];
    int jb = blockIdx.x * 32, db = blockIdx.y * 32;
#pragma unroll
    for (int i = 0; i < 4; ++i)
        t[threadIdx.y + i * 8][threadIdx.x] =
            e[(size_t)(db + threadIdx.y + i * 8) * NC + jb + threadIdx.x];
    __syncthreads();
#pragma unroll
    for (int i = 0; i < 4; ++i)
        eT[(size_t)(jb + threadIdx.y + i * 8) * DIM + db + threadIdx.x] =
            t[threadIdx.x][threadIdx.y + i * 8];
}

__global__ void row_norms_k(const float* __restrict__ x, float* __restrict__ norms) {
    int row  = blockIdx.x * 4 + (threadIdx.x >> 6);
    int lane = threadIdx.x & 63;
    const float4 v = ((const float4*)(x + (size_t)row * DIM))[lane];
    float s = v.x * v.x + v.y * v.y + v.z * v.z + v.w * v.w;
#pragma unroll
    for (int off = 32; off; off >>= 1) s += __shfl_down(s, off, 64);
    if (lane == 0) norms[row] = s;
}

__global__ __launch_bounds__(256, 4) void vq_main_k(
    const float* __restrict__ x, const float* __restrict__ e,
    const float* __restrict__ eT, const float* __restrict__ norms,
    const float* __restrict__ cHalf, float* __restrict__ qout,
    float* __restrict__ iout, float* __restrict__ lout, int useT)
{
    __shared__ float  As[2][32 * 68];
    __shared__ float4 Bs[2][512];
    const int tid  = threadIdx.x;
    const int row0 = blockIdx.x * 64;
    const int ty = tid >> 4, tx = tid & 15;
    const int ar = tid >> 2, ak = (tid & 3) * 4;
    const int bk = tid >> 4, bj = tid & 15;
    float bestv[4]; int bestj[4];
#pragma unroll
    for (int i = 0; i < 4; ++i) { bestv[i] = -3.4e38f; bestj[i] = 0; }
    float acc[4][4];
    float4 pa0, pa1, pb0, pb1;
    {
        const float* xp = x + (size_t)(row0 + ar) * DIM + ak;
        pa0 = *(const float4*)xp;
        pa1 = *(const float4*)(xp + 16);
        const float* ep = e + (size_t)bk * NC + bj * 4;
        pb0 = *(const float4*)ep;
        pb1 = *(const float4*)(ep + 16 * NC);
    }
    int buf = 0;
    for (int c = 0; c < 1024; ++c) {
        const int kc = c & 7;
#pragma unroll
        for (int q = 0; q < 4; ++q) As[buf][(ak + q) * 68 + ar]      = ((const float*)&pa0)[q];
#pragma unroll
        for (int q = 0; q < 4; ++q) As[buf][(16 + ak + q) * 68 + ar] = ((const float*)&pa1)[q];
        Bs[buf][bk * 16 + bj]        = pb0;
        Bs[buf][(bk + 16) * 16 + bj] = pb1;
        __syncthreads();
        if (c + 1 < 1024) {
            int j0n  = ((c + 1) >> 3) * 64;
            int kk0n = ((c + 1) & 7) * 32;
            const float* xp = x + (size_t)(row0 + ar) * DIM + kk0n + ak;
            pa0 = *(const float4*)xp;
            pa1 = *(const float4*)(xp + 16);
            const float* ep = e + (size_t)(kk0n + bk) * NC + j0n + bj * 4;
            pb0 = *(const float4*)ep;
            pb1 = *(const float4*)(ep + 16 * NC);
        }
        if (kc == 0) {
#pragma unroll
            for (int i = 0; i < 4; ++i)
#pragma unroll
                for (int j = 0; j < 4; ++j) acc[i][j] = 0.f;
        }
#pragma unroll
        for (int k = 0; k < 32; ++k) {
            float4 a = *(const float4*)&As[buf][k * 68 + ty * 4];
            float4 b = *(const float4*)&Bs[buf][k * 16 + tx];
            acc[0][0] += a.x * b.x; acc[0][1] += a.x * b.y; acc[0][2] += a.x * b.z; acc[0][3] += a.x * b.w;
            acc[1][0] += a.y * b.x; acc[1][1] += a.y * b.y; acc[1][2] += a.y * b.z; acc[1][3] += a.y * b.w;
            acc[2][0] += a.z * b.x; acc[2][1] += a.z * b.y; acc[2][2] += a.z * b.z; acc[2][3] += a.z * b.w;
            acc[3][0] += a.w * b.x; acc[3][1] += a.w * b.y; acc[3][2] += a.w * b.z; acc[3][3] += a.w * b.w;
        }
        if (kc == 7) {
            int j0 = (c >> 3) * 64;
            float4 ch = *(const float4*)&cHalf[j0 + tx * 4];
            int jb0 = j0 + tx * 4;
#pragma unroll
            for (int i = 0; i < 4; ++i)
#pragma unroll
                for (int j = 0; j < 4; ++j) {
                    float s = acc[i][j] - ((const float*)&ch)[j];
                    if (s > bestv[i]) { bestv[i] = s; bestj[i] = jb0 + j; }
                }
        }
        buf ^= 1;
    }
    __syncthreads();
    float* redv   = &As[0][0];
    int*   redj   = (int*)&As[0][1024];
    int*   idxbuf = (int*)&As[1][0];
#pragma unroll
    for (int i = 0; i < 4; ++i) {
        int r = ty * 4 + i;
        redv[r * 16 + tx] = bestv[i];
        redj[r * 16 + tx] = bestj[i];
    }
    __syncthreads();
    if (tid < 64) {
        float bvv = redv[tid * 16];
        int   bj2 = redj[tid * 16];
#pragma unroll
        for (int t = 1; t < 16; ++t) {
            float v = redv[tid * 16 + t];
            int   j = redj[tid * 16 + t];
            if (v > bvv || (v == bvv && j < bj2)) { bvv = v; bj2 = j; }
        }
        iout[row0 + tid] = (float)bj2;
        idxbuf[tid] = bj2;
        float rl = norms[row0 + tid] - 2.0f * bvv;
#pragma unroll
        for (int off = 32; off; off >>= 1) rl += __shfl_down(rl, off, 64);
        if (tid == 0) atomicAdd(lout, rl * LOSS_SCALE);
    }
    __syncthreads();
    {
        const int rr = tid >> 6, lane = tid & 63;
        for (int r = rr; r < 64; r += 4) {
            int j = idxbuf[r];
            float4 v;
            if (useT) {
                v = *(const float4*)&eT[(size_t)j * DIM + lane * 4];
            } else {
                int d = lane * 4;
                v.x = e[(size_t)d * NC + j];
                v.y = e[(size_t)(d + 1) * NC + j];
                v.z = e[(size_t)(d + 2) * NC + j];
                v.w = e[(size_t)(d + 3) * NC + j];
            }
            *(float4*)&qout[(size_t)(row0 + r) * DIM + lane * 4] = v;
        }
    }
}

// ======================= launch =======================

extern "C" void kernel_launch(void* const* d_in, const int* in_sizes, int n_in,
                              void* d_out, int out_size, void* d_ws, size_t ws_size,
                              hipStream_t stream) {
    const float* x = (const float*)d_in[0];   // [32768, 256]
    const float* e = (const float*)d_in[1];   // [256, 8192]

    float* qout = (float*)d_out;
    float* iout = qout + (size_t)NROW * DIM;
    float* lout = iout + NROW;

    char* ws = (char*)d_ws;
    const size_t offAh    = 0;                    // 33,554,432
    const size_t offBh    = offAh + 33554432;     //  8,388,608 (8192*512*2)
    const size_t offET    = offBh + 8388608;      //  8,388,608
    const size_t offNorms = offET + 8388608;      //    131,072
    const size_t offCH    = offNorms + 131072;    //     32,768
    const size_t offPV    = offCH + 32768;        //    524,288
    const size_t offPJ    = offPV + 524288;       //    524,288
    const size_t offPSV   = offPJ + 524288;       //    524,288
    const size_t offPV2   = offPSV + 524288;      //  1,048,576 (32*8192*4)
    const size_t offPJ2   = offPV2 + 1048576;     //  1,048,576
    const size_t offList  = offPJ2 + 1048576;     //     32,768
    const size_t offCnt   = offList + 32768;      //        256
    const size_t needFast = offCnt + 256;         // ~51.7 MB

    hipMemsetAsync(lout, 0, sizeof(float), stream);

    if (ws_size >= needFast) {
        unsigned short* Ah = (unsigned short*)(ws + offAh);
        unsigned short* Bh = (unsigned short*)(ws + offBh);
        float* eT    = (float*)(ws + offET);
        float* norms = (float*)(ws + offNorms);
        float* cHalf = (float*)(ws + offCH);
        float* pv    = (float*)(ws + offPV);
        int*   pj    = (int*)(ws + offPJ);
        float* psv   = (float*)(ws + offPSV);
        float* pv2   = (float*)(ws + offPV2);
        int*   pj2   = (int*)(ws + offPJ2);
        int*   list  = (int*)(ws + offList);
        int*   cnt   = (int*)(ws + offCnt);

        hipMemsetAsync(cnt, 0, sizeof(int), stream);
        prep_a_k<<<NROW / 4, 256, 0, stream>>>(x, Ah, norms);
        code_norms_k<<<NC / 256, 256, 0, stream>>>(e, cHalf);
        prep_b_k<<<dim3(NC / 32, DIM / 32), dim3(32, 8), 0, stream>>>(e, eT, Bh);
        // cheap pass: K=256 (hi.hi), 4 col-splits of 2048
        vq_gemm_k<8, 16, 2, false><<<1024, 256, 0, stream>>>(
            Ah, Bh, cHalf, pv, pj, psv, nullptr, nullptr);
        // merge + flag + finalize non-flagged
        vq_reduce_k<<<NROW / 64, 256, 0, stream>>>(
            pv, pj, psv, norms, eT, qout, iout, lout, list, cnt);
        // precise pass (K=768) on flagged rows: 32 col-splits of 256
        vq_gemm_k<24, 2, 5, true><<<(CAP / 128) * 32, 256, 0, stream>>>(
            Ah, Bh, cHalf, pv2, pj2, nullptr, list, cnt);
        vq_reduce2_k<<<CAP / 64, 256, 0, stream>>>(
            pv2, pj2, list, cnt, norms, eT, qout, iout, lout);
    } else {
        // round-1 fp32 fallback
        float* fws   = (float*)d_ws;
        float* norms = fws;
        float* cHalf = fws + NROW;
        float* eT    = fws + NROW + NC;
        size_t need_T = (size_t)(NROW + NC) * sizeof(float) + (size_t)NC * DIM * sizeof(float);
        int useT = (ws_size >= need_T) ? 1 : 0;
        row_norms_k<<<NROW / 4, 256, 0, stream>>>(x, norms);
        code_norms_k<<<NC / 256, 256, 0, stream>>>(e, cHalf);
        if (useT)
            transpose_k<<<dim3(NC / 32, DIM / 32), dim3(32, 8), 0, stream>>>(e, eT);
        vq_main_k<<<NROW / 64, 256, 0, stream>>>(x, e, eT, norms, cHalf, qout, iout, lout, useT);
    }
}

// Round 6
// 462.358 us; speedup vs baseline: 8.4825x; 1.3520x over previous
//
#include <hip/hip_runtime.h>
#include <hip/hip_fp16.h>

#define NROW 32768
#define DIM  256
#define NC   8192
#define CAP  16384                     // max rescued rows (expect ~4400)
#define MARGINF 0.5f                   // truncated-gap flag threshold (0.375 + q=0.125)
#define BIAS 512.0f                    // cheap-score bias: guarantees all cheap scores negative
#define ASTRIDE 544                    // A' row: [hi 256 | lo 256 | ones 32]
#define BSTRIDE 544                    // B' row: [hi 256 | lo 256 | ch 32]
#define LOSS_SCALE (1.0f / 8388608.0f)

typedef __attribute__((ext_vector_type(8))) _Float16 half8;
typedef __attribute__((ext_vector_type(4))) _Float16 half4;
typedef __attribute__((ext_vector_type(4))) float   floatx4;
typedef const __attribute__((address_space(1))) void* gas_p;
typedef __attribute__((address_space(3))) void*       las_p;

static __device__ __forceinline__ unsigned short f2hb(float f) {
    _Float16 h = (_Float16)f;
    unsigned short u;
    __builtin_memcpy(&u, &h, 2);
    return u;
}
static __device__ __forceinline__ unsigned umin_(unsigned a, unsigned b) { return a < b ? a : b; }
static __device__ __forceinline__ unsigned umax_(unsigned a, unsigned b) { return a > b ? a : b; }

// ======================= prep kernels (fast path) =======================

// rows -> norms + A' = [xhi | xlo | ones] f16, row stride 544
__global__ void prep_a_k(const float* __restrict__ x, unsigned short* __restrict__ Ah,
                         float* __restrict__ norms) {
    int row  = blockIdx.x * 4 + (threadIdx.x >> 6);
    int lane = threadIdx.x & 63;
    const float4 v = ((const float4*)(x + (size_t)row * DIM))[lane];
    float s = v.x * v.x + v.y * v.y + v.z * v.z + v.w * v.w;
#pragma unroll
    for (int off = 32; off; off >>= 1) s += __shfl_down(s, off, 64);
    if (lane == 0) norms[row] = s;
    ushort4 hi4 = make_ushort4(f2hb(v.x), f2hb(v.y), f2hb(v.z), f2hb(v.w));
    ushort4 lo4 = make_ushort4(f2hb(v.x - (float)(_Float16)v.x),
                               f2hb(v.y - (float)(_Float16)v.y),
                               f2hb(v.z - (float)(_Float16)v.z),
                               f2hb(v.w - (float)(_Float16)v.w));
    unsigned short* rp = Ah + (size_t)row * ASTRIDE;
    *(ushort4*)(rp + lane * 4)       = hi4;
    *(ushort4*)(rp + 256 + lane * 4) = lo4;
    if (lane < 8) {                    // ones block: [1,1,0,...,0] (32 halves)
        ushort4 ob = make_ushort4(0, 0, 0, 0);
        if (lane == 0) { ob.x = 0x3C00; ob.y = 0x3C00; }   // f16 1.0
        *(ushort4*)(rp + 512 + lane * 4) = ob;
    }
}

// per-code: fp32 cHalf (exact, for rescue) + ch block of B' (f16 pair, for cheap)
__global__ void code_norms_k(const float* __restrict__ e, unsigned short* __restrict__ Bh,
                             float* __restrict__ cHalf) {
    int j = blockIdx.x * 256 + threadIdx.x;
    float s = 0.f;
    for (int d = 0; d < DIM; ++d) { float v = e[(size_t)d * NC + j]; s += v * v; }
    cHalf[j] = 0.5f * s;
    float t = -0.5f * s - BIAS;
    unsigned short hi = f2hb(t);
    _Float16 hf; __builtin_memcpy(&hf, &hi, 2);
    unsigned short lo = f2hb(t - (float)hf);
    unsigned short* p = Bh + (size_t)j * BSTRIDE + 512;
    p[0] = hi; p[1] = lo;
    for (int k2 = 2; k2 < 32; ++k2) p[k2] = 0;
}

// e [dim][code] -> B' hi/lo sections (code-major, stride 544)
__global__ void prep_b_k(const float* __restrict__ e, unsigned short* __restrict__ Bh) {
    __shared__ float t[32][33];
    int jb = blockIdx.x * 32, db = blockIdx.y * 32;
#pragma unroll
    for (int i = 0; i < 4; ++i)
        t[threadIdx.y + i * 8][threadIdx.x] =
            e[(size_t)(db + threadIdx.y + i * 8) * NC + jb + threadIdx.x];
    __syncthreads();
#pragma unroll
    for (int i = 0; i < 4; ++i) {
        int j = jb + threadIdx.y + i * 8;
        int d = db + threadIdx.x;
        float val = t[threadIdx.x][threadIdx.y + i * 8];
        Bh[(size_t)j * BSTRIDE + d]       = f2hb(val);
        Bh[(size_t)j * BSTRIDE + 256 + d] = f2hb(val - (float)(_Float16)val);
    }
}

// ======================= templated GEMM+argmax kernel =======================
// Verified R3/R4 GEMM body. Block tile 128x128, wave tile 64x64 (4x4 frags of
// 16x16x32 f16 MFMA), LDS dbuf (parity = GLOBAL chunk counter -- safe for odd
// CHUNKS), global_load_lds width 16, 1 barrier/chunk.
// CHEAP (CHUNKS=9): c0-7 xhi.ehi, c8 const (1*ch_hi + 1*ch_lo = -0.5||e||^2-BIAS
//   folded into acc; margin analysis absorbs its ~1.2e-4 error). Epilogue:
//   branch-free uint-key top-2 min (key = (bits(score)&0xFFFFF800)|col11;
//   scores all negative so argmax = umin; tie -> smaller col).
// RESCUE (CHUNKS=24): c0-7 xhi.ehi, c8-15 xhi.elo, c16-23 xlo.ehi; NO const
//   chunk -- epilogue subtracts fp32 cHalf[col] exactly (R3/R4 precision:
//   the f16-pair const chunk flipped near-tie rows in R5). Indirect rows via
//   list[], early-exit past *cnt, float argmax epilogue.

template<int CHUNKS, int JT, int JSB, bool RESCUE>
__global__ __launch_bounds__(256, 2) void vq_gemm_k(
    const unsigned short* __restrict__ Ah, const unsigned short* __restrict__ Bh,
    const float* __restrict__ cHalf,
    float* __restrict__ pv, int* __restrict__ pj, float* __restrict__ psv,
    const int* __restrict__ list, const int* __restrict__ cnt)
{
    __shared__ __align__(16) _Float16 As[2][4096];
    __shared__ __align__(16) _Float16 Bs[2][4096];

    const int tid  = threadIdx.x;
    const int js   = blockIdx.x & ((1 << JSB) - 1);
    const int rb   = blockIdx.x >> JSB;
    const int row0 = rb * 128, col0 = js * (JT * 128);
    const int lane = tid & 63, l15 = lane & 15, lq = lane >> 4;
    const int wave = tid >> 6;
    const int wrow = (wave >> 1) * 64, wcol = (wave & 1) * 64;
    const int sr = tid >> 2, sp = (tid & 3) * 8;   // staging: row, k-part

    int nact = 0;
    if constexpr (RESCUE) {
        nact = *cnt;
        if (row0 >= nact) return;
    }

    const unsigned short *Abase0, *Abase1;
    if constexpr (RESCUE) {
        int i0 = row0 + sr, i1 = i0 + 64;
        int r0 = (i0 < nact) ? list[i0] : 0;
        int r1 = (i1 < nact) ? list[i1] : 0;
        Abase0 = Ah + (size_t)r0 * ASTRIDE + sp;
        Abase1 = Ah + (size_t)r1 * ASTRIDE + sp;
    } else {
        Abase0 = Ah + (size_t)(row0 + sr) * ASTRIDE + sp;
        Abase1 = Abase0 + 64 * ASTRIDE;
    }

    // cheap state: packed keys; rescue state: float best
    unsigned k1[16], k2[16];
    float bvf[16]; int bjf[16];
#pragma unroll
    for (int s = 0; s < 16; ++s) {
        k1[s] = 0xFFFFFFFFu; k2[s] = 0xFFFFFFFFu;
        bvf[s] = -3.4e38f; bjf[s] = 0;
    }

    const floatx4 fzero = {0.0f, 0.0f, 0.0f, 0.0f};

    for (int jt = 0; jt < JT; ++jt) {
        floatx4 acc[4][4];
#pragma unroll
        for (int rf = 0; rf < 4; ++rf)
#pragma unroll
            for (int cf = 0; cf < 4; ++cf) acc[rf][cf] = fzero;

        const unsigned short* Bbase = Bh + (size_t)(col0 + jt * 128 + sr) * BSTRIDE + sp;

        for (int c = 0; c < CHUNKS; ++c) {
            const int buf = (jt * CHUNKS + c) & 1;   // global parity: safe for odd CHUNKS
            int ac, bc;
            if constexpr (RESCUE) {
                if (c < 8)       { ac = c * 32;             bc = c * 32; }
                else if (c < 16) { ac = (c - 8) * 32;       bc = 256 + (c - 8) * 32; }
                else             { ac = 256 + (c - 16) * 32; bc = (c - 16) * 32; }
            } else {
                if (c < 8)       { ac = c * 32;             bc = c * 32; }
                else             { ac = 512;                bc = 512; }   // const chunk
            }

            _Float16* la = &As[buf][tid * 8];
            _Float16* lb = &Bs[buf][tid * 8];
            __builtin_amdgcn_global_load_lds((gas_p)(Abase0 + ac),                (las_p)la,          16, 0, 0);
            __builtin_amdgcn_global_load_lds((gas_p)(Abase1 + ac),                (las_p)(la + 2048), 16, 0, 0);
            __builtin_amdgcn_global_load_lds((gas_p)(Bbase + bc),                 (las_p)lb,          16, 0, 0);
            __builtin_amdgcn_global_load_lds((gas_p)(Bbase + 64 * BSTRIDE + bc),  (las_p)(lb + 2048), 16, 0, 0);
            __syncthreads();

            half8 af[4], bf[4];
#pragma unroll
            for (int rf = 0; rf < 4; ++rf)
                af[rf] = *(const half8*)&As[buf][(wrow + rf * 16 + l15) * 32 + lq * 8];
#pragma unroll
            for (int cf = 0; cf < 4; ++cf)
                bf[cf] = *(const half8*)&Bs[buf][(wcol + cf * 16 + l15) * 32 + lq * 8];
#pragma unroll
            for (int rf = 0; rf < 4; ++rf)
#pragma unroll
                for (int cf = 0; cf < 4; ++cf)
                    acc[rf][cf] = __builtin_amdgcn_mfma_f32_16x16x32_f16(
                        af[rf], bf[cf], acc[rf][cf], 0, 0, 0);
        }

        // ---- epilogue ----
        if constexpr (RESCUE) {
            const int colbase = col0 + jt * 128 + wcol;
#pragma unroll
            for (int cf = 0; cf < 4; ++cf) {
                const int col = colbase + cf * 16 + l15;
                const float ch = cHalf[col];            // exact fp32 subtraction
#pragma unroll
                for (int rf = 0; rf < 4; ++rf)
#pragma unroll
                    for (int r = 0; r < 4; ++r) {
                        float s = acc[rf][cf][r] - ch;
                        int slot = rf * 4 + r;
                        if (s > bvf[slot]) { bvf[slot] = s; bjf[slot] = col; }
                    }
            }
        } else {
            const unsigned colloc = (unsigned)(jt * 128 + wcol);
#pragma unroll
            for (int cf = 0; cf < 4; ++cf) {
                const unsigned colb = colloc + cf * 16 + l15;   // 11-bit within-split col
#pragma unroll
                for (int rf = 0; rf < 4; ++rf)
#pragma unroll
                    for (int r = 0; r < 4; ++r) {
                        unsigned key = (__float_as_uint(acc[rf][cf][r]) & 0xFFFFF800u) | colb;
                        int slot = rf * 4 + r;
                        unsigned t = umax_(key, k1[slot]);
                        k1[slot] = umin_(k1[slot], key);
                        k2[slot] = umin_(k2[slot], t);
                    }
            }
        }
    }

    // ---- cross-lane merge over the 16 lanes of each row-group ----
#pragma unroll
    for (int st = 1; st < 16; st <<= 1) {
#pragma unroll
        for (int s = 0; s < 16; ++s) {
            if constexpr (RESCUE) {
                float v2 = __shfl_xor(bvf[s], st, 64);
                int   j2 = __shfl_xor(bjf[s], st, 64);
                if (v2 > bvf[s] || (v2 == bvf[s] && j2 < bjf[s])) { bvf[s] = v2; bjf[s] = j2; }
            } else {
                unsigned o1 = (unsigned)__shfl_xor((int)k1[s], st, 64);
                unsigned o2 = (unsigned)__shfl_xor((int)k2[s], st, 64);
                unsigned t = umax_(k1[s], o1);
                k1[s] = umin_(k1[s], o1);
                k2[s] = umin_(umin_(k2[s], o2), t);
            }
        }
    }

    // ---- merge the two column-half waves per row through LDS ----
    __syncthreads();
    if constexpr (RESCUE) {
        float* mv = (float*)&As[0][0];       // [128][2]
        int*   mj = (int*)&Bs[0][0];
        if (l15 == 0) {
#pragma unroll
            for (int rf = 0; rf < 4; ++rf)
#pragma unroll
                for (int r = 0; r < 4; ++r) {
                    int rloc = wrow + rf * 16 + lq * 4 + r;
                    int slot = rf * 4 + r;
                    mv[rloc * 2 + (wave & 1)] = bvf[slot];
                    mj[rloc * 2 + (wave & 1)] = bjf[slot];
                }
        }
        __syncthreads();
        if (tid < 128) {
            float v0 = mv[tid * 2], v1 = mv[tid * 2 + 1];
            int   j0 = mj[tid * 2], j1 = mj[tid * 2 + 1];
            bool take1 = (v1 > v0) || (v1 == v0 && j1 < j0);
            pv[(size_t)js * CAP + row0 + tid] = take1 ? v1 : v0;
            pj[(size_t)js * CAP + row0 + tid] = take1 ? j1 : j0;
        }
    } else {
        unsigned* mk1 = (unsigned*)&As[0][0];    // [128][2]
        unsigned* mk2 = (unsigned*)&Bs[0][0];
        if (l15 == 0) {
#pragma unroll
            for (int rf = 0; rf < 4; ++rf)
#pragma unroll
                for (int r = 0; r < 4; ++r) {
                    int rloc = wrow + rf * 16 + lq * 4 + r;
                    int slot = rf * 4 + r;
                    mk1[rloc * 2 + (wave & 1)] = k1[slot];
                    mk2[rloc * 2 + (wave & 1)] = k2[slot];
                }
        }
        __syncthreads();
        if (tid < 128) {
            unsigned a1 = mk1[tid * 2], b1 = mk1[tid * 2 + 1];
            unsigned a2 = mk2[tid * 2], b2 = mk2[tid * 2 + 1];
            unsigned m1 = umin_(a1, b1);
            unsigned m2 = umin_(umin_(a2, b2), umax_(a1, b1));
            pv[(size_t)js * NROW + row0 + tid] = __uint_as_float(m1 & 0xFFFFF800u);
            pj[(size_t)js * NROW + row0 + tid] = (int)(m1 & 2047u) + js * (JT * 128);
            psv[(size_t)js * NROW + row0 + tid] = __uint_as_float(m2 & 0xFFFFF800u);
        }
    }
}

// ======================= cheap reduce: merge splits, flag, gather =======================

__global__ void vq_reduce_k(const float* __restrict__ pv, const int* __restrict__ pj,
                            const float* __restrict__ psv,
                            const float* __restrict__ norms, const unsigned short* __restrict__ Bh,
                            float* __restrict__ qout, float* __restrict__ iout,
                            float* __restrict__ lout, int* __restrict__ list,
                            int* __restrict__ cnt)
{
    __shared__ int jbuf[64];
    const int row0 = blockIdx.x * 64;
    const int tid = threadIdx.x;
    if (tid < 64) {
        int row = row0 + tid;
        float bv = pv[row]; int bj = pj[row]; float sv = psv[row];
#pragma unroll
        for (int s = 1; s < 4; ++s) {
            float v = pv[(size_t)s * NROW + row];
            int   j = pj[(size_t)s * NROW + row];
            float s2 = psv[(size_t)s * NROW + row];
            bool better = (v > bv) || (v == bv && j < bj);
            float loseBest = better ? bv : v;
            sv = fmaxf(fmaxf(sv, s2), loseBest);
            if (better) { bv = v; bj = j; }
        }
        bool flagged = (bv - sv) < MARGINF;
        if (flagged) {
            int idx = atomicAdd(cnt, 1);
            if (idx < CAP) {
                list[idx] = row;
                jbuf[tid] = -1;            // rescue pass will write this row
            } else {
                flagged = false;           // overflow: accept cheap result
            }
        }
        float rl = 0.f;
        if (!flagged) {
            iout[row] = (float)bj;
            jbuf[tid] = bj;
            // stored bv = trunc(s_biased) = s_biased + eps, eps in [0, 0.125): center with -q/2
            rl = norms[row] - 2.0f * (bv + BIAS - 0.0625f);
        }
#pragma unroll
        for (int off = 32; off; off >>= 1) rl += __shfl_down(rl, off, 64);
        if (tid == 0) atomicAdd(lout, rl * LOSS_SCALE);
    }
    __syncthreads();
    const int lane = tid & 63;
    for (int r = tid >> 6; r < 64; r += 4) {
        int j = jbuf[r];
        if (j >= 0) {
            const _Float16* bp = (const _Float16*)Bh + (size_t)j * BSTRIDE + lane * 4;
            half4 h = *(const half4*)bp;
            half4 l = *(const half4*)(bp + 256);
            float4 v;
            v.x = (float)h[0] + (float)l[0];
            v.y = (float)h[1] + (float)l[1];
            v.z = (float)h[2] + (float)l[2];
            v.w = (float)h[3] + (float)l[3];
            *(float4*)&qout[(size_t)(row0 + r) * DIM + lane * 4] = v;
        }
    }
}

// ======================= rescue reduce: merge 16 splits, finalize =======================

__global__ void vq_reduce2_k(const float* __restrict__ pv2, const int* __restrict__ pj2,
                             const int* __restrict__ list, const int* __restrict__ cnt,
                             const float* __restrict__ norms, const unsigned short* __restrict__ Bh,
                             float* __restrict__ qout, float* __restrict__ iout,
                             float* __restrict__ lout)
{
    __shared__ int rbuf[64], jb2[64];
    const int n = *cnt < CAP ? *cnt : CAP;
    const int i0 = blockIdx.x * 64;
    if (i0 >= n) return;
    const int tid = threadIdx.x;
    if (tid < 64) {
        int i = i0 + tid;
        float rl = 0.f;
        if (i < n) {
            float bv = pv2[i]; int bj = pj2[i];
#pragma unroll 4
            for (int s = 1; s < 16; ++s) {
                float v = pv2[(size_t)s * CAP + i];
                int   j = pj2[(size_t)s * CAP + i];
                if (v > bv || (v == bv && j < bj)) { bv = v; bj = j; }
            }
            int row = list[i];
            iout[row] = (float)bj;
            rbuf[tid] = row;
            jb2[tid]  = bj;
            rl = norms[row] - 2.0f * bv;   // precise unbiased score
        } else {
            rbuf[tid] = -1;
        }
#pragma unroll
        for (int off = 32; off; off >>= 1) rl += __shfl_down(rl, off, 64);
        if (tid == 0) atomicAdd(lout, rl * LOSS_SCALE);
    }
    __syncthreads();
    const int lane = tid & 63;
    for (int r = tid >> 6; r < 64; r += 4) {
        int row = rbuf[r];
        if (row >= 0) {
            const _Float16* bp = (const _Float16*)Bh + (size_t)jb2[r] * BSTRIDE + lane * 4;
            half4 h = *(const half4*)bp;
            half4 l = *(const half4*)(bp + 256);
            float4 v;
            v.x = (float)h[0] + (float)l[0];
            v.y = (float)h[1] + (float)l[1];
            v.z = (float)h[2] + (float)l[2];
            v.w = (float)h[3] + (float)l[3];
            *(float4*)&qout[(size_t)row * DIM + lane * 4] = v;
        }
    }
}

// ======================= fallback fp32 path (round-1, known-good) =======================

__global__ void transpose_k(const float* __restrict__ e, float* __restrict__ eT) {
    __shared__ float t[32][33];
    int jb = blockIdx.x * 32, db = blockIdx.y * 32;
#pragma unroll
    for (int i = 0; i < 4; ++i)
        t[threadIdx.y + i * 8][threadIdx.x] =
            e[(size_t)(db + threadIdx.y + i * 8) * NC + jb + threadIdx.x];
    __syncthreads();
#pragma unroll
    for (int i = 0; i < 4; ++i)
        eT[(size_t)(jb + threadIdx.y + i * 8) * DIM + db + threadIdx.x] =
            t[threadIdx.x][threadIdx.y + i * 8];
}

__global__ void row_norms_k(const float* __restrict__ x, float* __restrict__ norms) {
    int row  = blockIdx.x * 4 + (threadIdx.x >> 6);
    int lane = threadIdx.x & 63;
    const float4 v = ((const float4*)(x + (size_t)row * DIM))[lane];
    float s = v.x * v.x + v.y * v.y + v.z * v.z + v.w * v.w;
#pragma unroll
    for (int off = 32; off; off >>= 1) s += __shfl_down(s, off, 64);
    if (lane == 0) norms[row] = s;
}

__global__ void code_norms_fb_k(const float* __restrict__ e, float* __restrict__ cHalf) {
    int j = blockIdx.x * 256 + threadIdx.x;
    float s = 0.f;
    for (int d = 0; d < DIM; ++d) { float v = e[(size_t)d * NC + j]; s += v * v; }
    cHalf[j] = 0.5f * s;
}

__global__ __launch_bounds__(256, 4) void vq_main_k(
    const float* __restrict__ x, const float* __restrict__ e,
    const float* __restrict__ eT, const float* __restrict__ norms,
    const float* __restrict__ cHalf, float* __restrict__ qout,
    float* __restrict__ iout, float* __restrict__ lout, int useT)
{
    __shared__ float  As[2][32 * 68];
    __shared__ float4 Bs[2][512];
    const int tid  = threadIdx.x;
    const int row0 = blockIdx.x * 64;
    const int ty = tid >> 4, tx = tid & 15;
    const int ar = tid >> 2, ak = (tid & 3) * 4;
    const int bk = tid >> 4, bj = tid & 15;
    float bestv[4]; int bestj[4];
#pragma unroll
    for (int i = 0; i < 4; ++i) { bestv[i] = -3.4e38f; bestj[i] = 0; }
    float acc[4][4];
    float4 pa0, pa1, pb0, pb1;
    {
        const float* xp = x + (size_t)(row0 + ar) * DIM + ak;
        pa0 = *(const float4*)xp;
        pa1 = *(const float4*)(xp + 16);
        const float* ep = e + (size_t)bk * NC + bj * 4;
        pb0 = *(const float4*)ep;
        pb1 = *(const float4*)(ep + 16 * NC);
    }
    int buf = 0;
    for (int c = 0; c < 1024; ++c) {
        const int kc = c & 7;
#pragma unroll
        for (int q = 0; q < 4; ++q) As[buf][(ak + q) * 68 + ar]      = ((const float*)&pa0)[q];
#pragma unroll
        for (int q = 0; q < 4; ++q) As[buf][(16 + ak + q) * 68 + ar] = ((const float*)&pa1)[q];
        Bs[buf][bk * 16 + bj]        = pb0;
        Bs[buf][(bk + 16) * 16 + bj] = pb1;
        __syncthreads();
        if (c + 1 < 1024) {
            int j0n  = ((c + 1) >> 3) * 64;
            int kk0n = ((c + 1) & 7) * 32;
            const float* xp = x + (size_t)(row0 + ar) * DIM + kk0n + ak;
            pa0 = *(const float4*)xp;
            pa1 = *(const float4*)(xp + 16);
            const float* ep = e + (size_t)(kk0n + bk) * NC + j0n + bj * 4;
            pb0 = *(const float4*)ep;
            pb1 = *(const float4*)(ep + 16 * NC);
        }
        if (kc == 0) {
#pragma unroll
            for (int i = 0; i < 4; ++i)
#pragma unroll
                for (int j = 0; j < 4; ++j) acc[i][j] = 0.f;
        }
#pragma unroll
        for (int k = 0; k < 32; ++k) {
            float4 a = *(const float4*)&As[buf][k * 68 + ty * 4];
            float4 b = *(const float4*)&Bs[buf][k * 16 + tx];
            acc[0][0] += a.x * b.x; acc[0][1] += a.x * b.y; acc[0][2] += a.x * b.z; acc[0][3] += a.x * b.w;
            acc[1][0] += a.y * b.x; acc[1][1] += a.y * b.y; acc[1][2] += a.y * b.z; acc[1][3] += a.y * b.w;
            acc[2][0] += a.z * b.x; acc[2][1] += a.z * b.y; acc[2][2] += a.z * b.z; acc[2][3] += a.z * b.w;
            acc[3][0] += a.w * b.x; acc[3][1] += a.w * b.y; acc[3][2] += a.w * b.z; acc[3][3] += a.w * b.w;
        }
        if (kc == 7) {
            int j0 = (c >> 3) * 64;
            float4 ch = *(const float4*)&cHalf[j0 + tx * 4];
            int jb0 = j0 + tx * 4;
#pragma unroll
            for (int i = 0; i < 4; ++i)
#pragma unroll
                for (int j = 0; j < 4; ++j) {
                    float s = acc[i][j] - ((const float*)&ch)[j];
                    if (s > bestv[i]) { bestv[i] = s; bestj[i] = jb0 + j; }
                }
        }
        buf ^= 1;
    }
    __syncthreads();
    float* redv   = &As[0][0];
    int*   redj   = (int*)&As[0][1024];
    int*   idxbuf = (int*)&As[1][0];
#pragma unroll
    for (int i = 0; i < 4; ++i) {
        int r = ty * 4 + i;
        redv[r * 16 + tx] = bestv[i];
        redj[r * 16 + tx] = bestj[i];
    }
    __syncthreads();
    if (tid < 64) {
        float bvv = redv[tid * 16];
        int   bj2 = redj[tid * 16];
#pragma unroll
        for (int t = 1; t < 16; ++t) {
            float v = redv[tid * 16 + t];
            int   j = redj[tid * 16 + t];
            if (v > bvv || (v == bvv && j < bj2)) { bvv = v; bj2 = j; }
        }
        iout[row0 + tid] = (float)bj2;
        idxbuf[tid] = bj2;
        float rl = norms[row0 + tid] - 2.0f * bvv;
#pragma unroll
        for (int off = 32; off; off >>= 1) rl += __shfl_down(rl, off, 64);
        if (tid == 0) atomicAdd(lout, rl * LOSS_SCALE);
    }
    __syncthreads();
    {
        const int rr = tid >> 6, lane = tid & 63;
        for (int r = rr; r < 64; r += 4) {
            int j = idxbuf[r];
            float4 v;
            if (useT) {
                v = *(const float4*)&eT[(size_t)j * DIM + lane * 4];
            } else {
                int d = lane * 4;
                v.x = e[(size_t)d * NC + j];
                v.y = e[(size_t)(d + 1) * NC + j];
                v.z = e[(size_t)(d + 2) * NC + j];
                v.w = e[(size_t)(d + 3) * NC + j];
            }
            *(float4*)&qout[(size_t)(row0 + r) * DIM + lane * 4] = v;
        }
    }
}

// ======================= launch =======================

extern "C" void kernel_launch(void* const* d_in, const int* in_sizes, int n_in,
                              void* d_out, int out_size, void* d_ws, size_t ws_size,
                              hipStream_t stream) {
    const float* x = (const float*)d_in[0];   // [32768, 256]
    const float* e = (const float*)d_in[1];   // [256, 8192]

    float* qout = (float*)d_out;
    float* iout = qout + (size_t)NROW * DIM;
    float* lout = iout + NROW;

    char* ws = (char*)d_ws;
    const size_t offAh    = 0;                    // 32768*544*2 = 35,651,584
    const size_t offBh    = offAh + 35651584;     //  8192*544*2 =  8,912,896
    const size_t offNorms = offBh + 8912896;      //    131,072
    const size_t offCH    = offNorms + 131072;    //     32,768 (fp32 cHalf, rescue)
    const size_t offPV    = offCH + 32768;        //    524,288 (4 splits x NROW)
    const size_t offPJ    = offPV + 524288;       //    524,288
    const size_t offPSV   = offPJ + 524288;       //    524,288
    const size_t offPV2   = offPSV + 524288;      //  1,048,576 (16 x CAP x 4)
    const size_t offPJ2   = offPV2 + 1048576;     //  1,048,576
    const size_t offList  = offPJ2 + 1048576;     //     65,536
    const size_t offCnt   = offList + 65536;      //        256
    const size_t needFast = offCnt + 256;         // ~48.5 MB (proven: >=51.7 MB available)

    hipMemsetAsync(lout, 0, sizeof(float), stream);

    if (ws_size >= needFast) {
        unsigned short* Ah = (unsigned short*)(ws + offAh);
        unsigned short* Bh = (unsigned short*)(ws + offBh);
        float* norms = (float*)(ws + offNorms);
        float* cHalf = (float*)(ws + offCH);
        float* pv    = (float*)(ws + offPV);
        int*   pj    = (int*)(ws + offPJ);
        float* psv   = (float*)(ws + offPSV);
        float* pv2   = (float*)(ws + offPV2);
        int*   pj2   = (int*)(ws + offPJ2);
        int*   list  = (int*)(ws + offList);
        int*   cnt   = (int*)(ws + offCnt);

        hipMemsetAsync(cnt, 0, sizeof(int), stream);
        prep_a_k<<<NROW / 4, 256, 0, stream>>>(x, Ah, norms);
        code_norms_k<<<NC / 256, 256, 0, stream>>>(e, Bh, cHalf);
        prep_b_k<<<dim3(NC / 32, DIM / 32), dim3(32, 8), 0, stream>>>(e, Bh);
        // cheap pass: K=256 hi.hi + folded (-0.5||e||^2 - BIAS); 4 col-splits of 2048
        vq_gemm_k<9, 16, 2, false><<<1024, 256, 0, stream>>>(
            Ah, Bh, cHalf, pv, pj, psv, nullptr, nullptr);
        // merge + flag + finalize non-flagged
        vq_reduce_k<<<NROW / 64, 256, 0, stream>>>(
            pv, pj, psv, norms, Bh, qout, iout, lout, list, cnt);
        // precise pass (K=768, exact fp32 cHalf) on flagged rows: 16 col-splits of 512
        vq_gemm_k<24, 4, 4, true><<<(CAP / 128) * 16, 256, 0, stream>>>(
            Ah, Bh, cHalf, pv2, pj2, nullptr, list, cnt);
        vq_reduce2_k<<<CAP / 64, 256, 0, stream>>>(
            pv2, pj2, list, cnt, norms, Bh, qout, iout, lout);
    } else {
        // round-1 fp32 fallback
        float* fws   = (float*)d_ws;
        float* norms = fws;
        float* cHalf = fws + NROW;
        float* eT    = fws + NROW + NC;
        size_t need_T = (size_t)(NROW + NC) * sizeof(float) + (size_t)NC * DIM * sizeof(float);
        int useT = (ws_size >= need_T) ? 1 : 0;
        row_norms_k<<<NROW / 4, 256, 0, stream>>>(x, norms);
        code_norms_fb_k<<<NC / 256, 256, 0, stream>>>(e, cHalf);
        if (useT)
            transpose_k<<<dim3(NC / 32, DIM / 32), dim3(32, 8), 0, stream>>>(e, eT);
        vq_main_k<<<NROW / 64, 256, 0, stream>>>(x, e, eT, norms, cHalf, qout, iout, lout, useT);
    }
}